// Round 17
// baseline (222.946 us; speedup 1.0000x reference)
//
#include <hip/hip_runtime.h>
#include <stdint.h>

#define H 1024
#define LSEQ 4096
#define NBATCH 4
#define MT (NBATCH*LSEQ)   // 16384 rows total

typedef __attribute__((ext_vector_type(8))) short bf16x8;
typedef __attribute__((ext_vector_type(4))) short s16x4;
typedef __attribute__((ext_vector_type(4))) float f32x4;

static __device__ __forceinline__ unsigned short f2bf(float f){
  union { float f; unsigned u; } v; v.f = f;
  unsigned u = v.u;
  return (unsigned short)((u + 0x7FFFu + ((u >> 16) & 1u)) >> 16);  // RNE
}
static __device__ __forceinline__ float bf2f(unsigned short h){
  union { unsigned u; float f; } v; v.u = ((unsigned)h) << 16;
  return v.f;
}
static __device__ __forceinline__ void g2l16(const void* g, void* l){
  __builtin_amdgcn_global_load_lds((const __attribute__((address_space(1))) void*)g,
                                   (__attribute__((address_space(3))) void*)l, 16, 0, 0);
}
static __device__ __forceinline__ f32x4 mfma16(bf16x8 a, bf16x8 b, f32x4 c){
  return __builtin_amdgcn_mfma_f32_16x16x32_bf16(a, b, c, 0, 0, 0);
}

// ---------------- fused: weight prep (blocks 0..4095) + x->bf16 (4096..8191) ---
struct P4 { const float* pw[4]; const float* dw[4]; const float* db[4]; const float* pb[4]; };

__global__ __launch_bounds__(256) void prepcvt(P4 a, const float* __restrict__ x,
    short* __restrict__ wb, float* __restrict__ bo, short* __restrict__ xb){
  const int bid = blockIdx.x, t = threadIdx.x;
  if (bid < 4096){
    __shared__ float red[256];
    const int p = bid >> 10, j = bid & 1023;
    const float* row = a.pw[p] + (size_t)j * H;
    const float* dwp = a.dw[p];
    const float* dbp = a.db[p];
    float acc = 0.f;
    #pragma unroll
    for (int k = 0; k < 4; ++k){
      int i = k*256 + t;
      float pv = row[i];
      wb[((size_t)p*H + j)*H + i] = (short)f2bf(pv * dwp[i]);
      acc += dbp[i] * pv;
    }
    red[t] = acc; __syncthreads();
    for (int s = 128; s > 0; s >>= 1){
      if (t < s) red[t] += red[t+s];
      __syncthreads();
    }
    if (t == 0) bo[p*H + j] = a.pb[p][j] + red[0];
  } else {
    const size_t base = ((size_t)(bid - 4096) * 4096) + (size_t)t * 16;
    #pragma unroll
    for (int h2 = 0; h2 < 2; ++h2){
      const float4* p = (const float4*)(x + base + h2*8);
      float4 u = p[0], v = p[1];
      bf16x8 o;
      o[0]=(short)f2bf(u.x); o[1]=(short)f2bf(u.y); o[2]=(short)f2bf(u.z); o[3]=(short)f2bf(u.w);
      o[4]=(short)f2bf(v.x); o[5]=(short)f2bf(v.y); o[6]=(short)f2bf(v.z); o[7]=(short)f2bf(v.w);
      *(bf16x8*)(xb + base + h2*8) = o;
    }
  }
}

// ============== 256x256 tile, BK=64, 8-wave, 2-phase counted-vmcnt GEMM ========
// R6/R10-proven structure (1010 TF). DO NOT restructure the K-loop.
// R17: intra-XCD traversal flipped to m-fastest (each XCD pins a B-strip in its
// private L2 and reuses it 64-96x; A streams once via die-level L3).
// MODE 0: N=3072 fused k|q|v. p=1 -> QB holds UNMASKED fp32-softmaxed query
//         weights (shift-free); mask handled in attd_k. p=0/2 -> KT/VT [B][H][L].
// MODE 1: N=1024, fp32 out [M][H].
template<int MODE, int NBLK>
__global__ __launch_bounds__(512, 2) void gemm8(const short* __restrict__ A,
    const short* __restrict__ WBp, const float* __restrict__ bia,
    short* __restrict__ oq, short* __restrict__ okT, short* __restrict__ ovT,
    float* __restrict__ ofin){
  __shared__ __align__(16) short lsm[2][2][256*64];

  const int nwg = NBLK * 64;
  const int cpx = nwg >> 3;
  const int bid = blockIdx.x;
  const int swz = (bid & 7) * cpx + (bid >> 3);   // XCD-contiguous chunks
  const int nb = swz >> 6, mb = swz & 63;         // m fastest within XCD -> B-strip L2-pinned
  const int m0 = mb * 256, n0 = nb * 256;

  const int tid  = threadIdx.x;
  const int lane = tid & 63;
  const int w    = tid >> 6;            // 0..7
  const int wm   = w >> 2, wn = w & 3;  // 2 x 4 wave grid; per-wave out 128x64
  const int q4 = lane >> 4, r16 = lane & 15;
  const int rl = lane >> 3, sl = lane & 7;
  const int srcsw = ((sl ^ rl) << 3);   // pre-swizzled global source slot

#define STAGE_A(BUF_, Q_, KB_) \
  g2l16(A + (size_t)(m0 + (Q_)*64 + w*8 + rl)*H + (KB_) + srcsw, \
        &lsm[0][BUF_][((Q_)*64 + w*8)*64])
#define STAGE_B(BUF_, Q_, KB_) \
  g2l16(WBp + (size_t)(n0 + (Q_)*64 + w*8 + rl)*H + (KB_) + srcsw, \
        &lsm[1][BUF_][((Q_)*64 + w*8)*64])
#define RD_A(dst, BUF_, MI8, KK) { const int row_ = wm*128 + (MI8)*16 + r16; \
  dst = *(const bf16x8*)&lsm[0][BUF_][row_*64 + ((((KK)*4+q4) ^ (row_&7))<<3)]; }
#define RD_B(dst, BUF_, NI4, KK) { const int row_ = wn*64 + (NI4)*16 + r16; \
  dst = *(const bf16x8*)&lsm[1][BUF_][row_*64 + ((((KK)*4+q4) ^ (row_&7))<<3)]; }

  f32x4 acc[8][4] = {};
  bf16x8 aF[4][2], bFa[2][2], bFb[2][2];

  // prologue: stage tile 0 (B quarters first, then A in first-needed order)
  STAGE_B(0,0,0); STAGE_B(0,1,0); STAGE_B(0,2,0); STAGE_B(0,3,0);
  STAGE_A(0,0,0); STAGE_A(0,2,0); STAGE_A(0,1,0); STAGE_A(0,3,0);
  asm volatile("s_waitcnt vmcnt(2)" ::: "memory");
  __builtin_amdgcn_s_barrier();

  #pragma unroll 2
  for (int t = 0; t < 16; ++t){
    const int buf = t & 1, sbuf = buf ^ 1;
    const int skb = ((t < 15) ? (t + 1) : 15) << 6;

    // ---- phase AB: full N, first M-half (A quarters q0/q2) ----
    #pragma unroll
    for (int mi = 0; mi < 4; ++mi){ RD_A(aF[mi][0], buf, mi, 0); RD_A(aF[mi][1], buf, mi, 1); }
    #pragma unroll
    for (int ni = 0; ni < 2; ++ni){ RD_B(bFa[ni][0], buf, ni, 0); RD_B(bFa[ni][1], buf, ni, 1); }
    #pragma unroll
    for (int ni = 0; ni < 2; ++ni){ RD_B(bFb[ni][0], buf, 2+ni, 0); RD_B(bFb[ni][1], buf, 2+ni, 1); }
    STAGE_B(sbuf, 0, skb); STAGE_B(sbuf, 1, skb);
    STAGE_B(sbuf, 2, skb); STAGE_B(sbuf, 3, skb);
    __builtin_amdgcn_s_setprio(1);
    #pragma unroll
    for (int kk = 0; kk < 2; ++kk)
      #pragma unroll
      for (int mi = 0; mi < 4; ++mi){
        #pragma unroll
        for (int ni = 0; ni < 2; ++ni)
          acc[mi][ni] = mfma16(aF[mi][kk], bFa[ni][kk], acc[mi][ni]);
        #pragma unroll
        for (int ni = 0; ni < 2; ++ni)
          acc[mi][2+ni] = mfma16(aF[mi][kk], bFb[ni][kk], acc[mi][2+ni]);
      }
    __builtin_amdgcn_s_setprio(0);
    asm volatile("s_waitcnt vmcnt(4)" ::: "memory");   // A q1/q3 of tile t landed
    __builtin_amdgcn_s_barrier();

    // ---- phase CD: full N, second M-half (A quarters q1/q3) ----
    #pragma unroll
    for (int mi = 0; mi < 4; ++mi){ RD_A(aF[mi][0], buf, 4+mi, 0); RD_A(aF[mi][1], buf, 4+mi, 1); }
    STAGE_A(sbuf, 0, skb); STAGE_A(sbuf, 2, skb);
    STAGE_A(sbuf, 1, skb); STAGE_A(sbuf, 3, skb);
    __builtin_amdgcn_s_setprio(1);
    #pragma unroll
    for (int kk = 0; kk < 2; ++kk)
      #pragma unroll
      for (int mi = 0; mi < 4; ++mi){
        #pragma unroll
        for (int ni = 0; ni < 2; ++ni)
          acc[4+mi][ni] = mfma16(aF[mi][kk], bFa[ni][kk], acc[4+mi][ni]);
        #pragma unroll
        for (int ni = 0; ni < 2; ++ni)
          acc[4+mi][2+ni] = mfma16(aF[mi][kk], bFb[ni][kk], acc[4+mi][2+ni]);
      }
    __builtin_amdgcn_s_setprio(0);
    asm volatile("s_waitcnt vmcnt(2)" ::: "memory");   // next tile's B + A q0/q2 landed
    __builtin_amdgcn_s_barrier();
  }
#undef STAGE_A
#undef STAGE_B
#undef RD_A
#undef RD_B

  // ---------------- epilogue ----------------
  if (MODE == 1){
    #pragma unroll
    for (int ni4 = 0; ni4 < 4; ++ni4){
      const int n = n0 + wn*64 + ni4*16 + r16;
      const float bv = bia[n];
      #pragma unroll
      for (int mi8 = 0; mi8 < 8; ++mi8){
        const int mbse = m0 + wm*128 + mi8*16 + q4*4;
        #pragma unroll
        for (int j = 0; j < 4; ++j)
          ofin[(size_t)(mbse+j)*H + n] = acc[mi8][ni4][j] + bv;
      }
    }
  } else {
    const int p = n0 >> 10;
    if (p == 1){
      // queries: shift-free fp32 softmax over the head's 64 channels (4 regs x
      // 16 lanes, constant q4,j), UNMASKED -> attd_k substitutes masked rows.
      #pragma unroll
      for (int ni4 = 0; ni4 < 4; ++ni4){
        const float bv = bia[n0 + wn*64 + ni4*16 + r16];
        #pragma unroll
        for (int mi8 = 0; mi8 < 8; ++mi8)
          #pragma unroll
          for (int j = 0; j < 4; ++j)
            acc[mi8][ni4][j] += bv;
      }
      #pragma unroll
      for (int mi8 = 0; mi8 < 8; ++mi8){
        #pragma unroll
        for (int j = 0; j < 4; ++j){
          float e0 = __expf(acc[mi8][0][j]);
          float e1 = __expf(acc[mi8][1][j]);
          float e2 = __expf(acc[mi8][2][j]);
          float e3 = __expf(acc[mi8][3][j]);
          float s = e0 + e1 + e2 + e3;
          s += __shfl_xor(s, 1);
          s += __shfl_xor(s, 2);
          s += __shfl_xor(s, 4);
          s += __shfl_xor(s, 8);
          const float inv = 1.0f / s;
          acc[mi8][0][j] = e0*inv;
          acc[mi8][1][j] = e1*inv;
          acc[mi8][2][j] = e2*inv;
          acc[mi8][3][j] = e3*inv;
        }
      }
      #pragma unroll
      for (int ni4 = 0; ni4 < 4; ++ni4){
        const int ch = (n0 & 1023) + wn*64 + ni4*16 + r16;
        #pragma unroll
        for (int mi8 = 0; mi8 < 8; ++mi8){
          const int mbse = m0 + wm*128 + mi8*16 + q4*4;
          #pragma unroll
          for (int j = 0; j < 4; ++j)
            oq[(size_t)(mbse+j)*H + ch] = (short)f2bf(acc[mi8][ni4][j]);
        }
      }
    } else {                                      // k/v -> transposed [B][H][L] via LDS stage
      asm volatile("s_waitcnt vmcnt(0)" ::: "memory");
      __syncthreads();
      char* sC = (char*)&lsm[0][0][0];            // 128 KiB = 256 ch x 256 m bf16, 512B rows
      #pragma unroll
      for (int ni4 = 0; ni4 < 4; ++ni4){
        const int cr = wn*64 + ni4*16 + r16;      // tile row = channel
        const float bv = bia[n0 + cr];
        #pragma unroll
        for (int mi8 = 0; mi8 < 8; ++mi8){
          const int s8 = wm*32 + mi8*4 + q4;      // 8B slot along m
          s16x4 v;
          #pragma unroll
          for (int j = 0; j < 4; ++j) v[j] = (short)f2bf(acc[mi8][ni4][j] + bv);
          *(s16x4*)(sC + cr*512 + ((s8 ^ ((cr & 7) << 1)) << 3)) = v;
        }
      }
      __syncthreads();
      short* ot = (p == 0) ? okT : ovT;
      const int ch0 = n0 & 1023, bb = m0 >> 12, lp0 = m0 & 4095;
      const int c = lane & 31;
      #pragma unroll
      for (int it = 0; it < 16; ++it){
        const int cr = it*16 + w*2 + (lane >> 5);
        bf16x8 vv = *(bf16x8*)(sC + cr*512 + ((c ^ (cr & 7)) << 4));
        *(bf16x8*)&ot[((size_t)bb*H + ch0 + cr)*LSEQ + lp0 + c*8] = vv;
      }
    }
  }
}

// ------- context partial over a 512-L chunk, fixed-shift softmax ---------------
// 256-thread blocks, serial 8-kc loop, double-buffered stage-ahead (R14-proven).
// w = mask ? exp(k-8) : 0 (scale cancels in (Sum w*v)/(Sum w)).
__global__ __launch_bounds__(256) void ctx_k(const short* __restrict__ kT,
    const short* __restrict__ vT, const int* __restrict__ mask,
    float* __restrict__ ctxP, float* __restrict__ dloc){
  const int lc = blockIdx.x, h = blockIdx.y, b = blockIdx.z;   // lc 0..7
  __shared__ __align__(16) short lK[2][64*64];
  __shared__ __align__(16) short lV[2][64*64];
  __shared__ int sMk[2][64];
  __shared__ float sDen[4][64];
  const int tid = threadIdx.x, lane = tid & 63, w = tid >> 6;  // w 0..3
  const short* kb = kT + (size_t)(b*16 + h)*64*LSEQ;
  const short* vb = vT + (size_t)(b*16 + h)*64*LSEQ;
  const int l0 = lc*512;
  const int sl = lane & 7, rl = lane >> 3;
  const int lsw = ((sl ^ rl) << 3);

#define CSTAGE(BUF_, KC_) { const int lb_ = l0 + (KC_)*64; \
  const int r0_ = (w*2)*8 + rl, r1_ = (w*2+1)*8 + rl; \
  g2l16(kb + (size_t)r0_*LSEQ + lb_ + lsw, &lK[BUF_][(w*2)*512]); \
  g2l16(vb + (size_t)r0_*LSEQ + lb_ + lsw, &lV[BUF_][(w*2)*512]); \
  g2l16(kb + (size_t)r1_*LSEQ + lb_ + lsw, &lK[BUF_][(w*2+1)*512]); \
  g2l16(vb + (size_t)r1_*LSEQ + lb_ + lsw, &lV[BUF_][(w*2+1)*512]); \
  if (tid < 64) sMk[BUF_][tid] = mask[(size_t)b*LSEQ + lb_ + tid]; }

  f32x4 acc[4] = {};
  float dsum = 0.f;

  // prologue: stage kc=0 into buf 0
  CSTAGE(0, 0);
  asm volatile("s_waitcnt vmcnt(0) lgkmcnt(0)" ::: "memory");
  __builtin_amdgcn_s_barrier();

  for (int kc = 0; kc < 8; ++kc){
    const int buf = kc & 1, sbuf = buf ^ 1;
    if (kc < 7) CSTAGE(sbuf, kc + 1);             // stage-ahead: latency hidden under below
    { // in-place transform lK[buf]: k -> mask ? exp(k-8) : 0, bf16; local denom
      const int row = lane;
      #pragma unroll
      for (int k2 = 0; k2 < 2; ++k2){
        const int slog = w*2 + k2;
        const int sp = slog ^ (row & 7);
        bf16x8 v = *(bf16x8*)&lK[buf][row*64 + (sp<<3)];
        bf16x8 o;
        #pragma unroll
        for (int e = 0; e < 8; ++e){
          const float f = bf2f((unsigned short)v[e]);
          const float we = sMk[buf][slog*8+e] ? __expf(f - 8.0f) : 0.0f;
          dsum += we;
          o[e] = (short)f2bf(we);
        }
        *(bf16x8*)&lK[buf][row*64 + (sp<<3)] = o;
      }
    }
    asm volatile("s_waitcnt lgkmcnt(0)" ::: "memory");  // my transform writes done
    __builtin_amdgcn_s_barrier();                       // all transforms visible
    {
      const int q4 = lane >> 4, r16 = lane & 15;
      #pragma unroll
      for (int kk = 0; kk < 2; ++kk){
        const int slog = kk*4 + q4;
        const int rowA = w*16 + r16;
        bf16x8 a = *(bf16x8*)&lK[buf][rowA*64 + ((slog ^ (rowA & 7))<<3)];
        #pragma unroll
        for (int ni = 0; ni < 4; ++ni){
          const int rowB = ni*16 + r16;
          bf16x8 bv = *(bf16x8*)&lV[buf][rowB*64 + ((slog ^ (rowB & 7))<<3)];
          acc[ni] = mfma16(a, bv, acc[ni]);
        }
      }
    }
    asm volatile("s_waitcnt vmcnt(0) lgkmcnt(0)" ::: "memory");  // kc+1 resident
    __builtin_amdgcn_s_barrier();
  }
#undef CSTAGE

  const int q4 = lane >> 4, r16 = lane & 15;
  float* op = ctxP + (((size_t)(b*16 + h)*8 + lc) << 12);
  #pragma unroll
  for (int ni = 0; ni < 4; ++ni){
    const int d = ni*16 + r16;
    #pragma unroll
    for (int j = 0; j < 4; ++j){
      const int c = w*16 + q4*4 + j;
      op[c*64 + d] = acc[ni][j];
    }
  }
  sDen[w][lane] = dsum;
  __syncthreads();
  if (tid < 64){
    const int idx = (((b*16 + h)*8 + lc) << 6) + tid;
    dloc[idx] = sDen[0][tid] + sDen[1][tid] + sDen[2][tid] + sDen[3][tid];
  }
}

// ------- attended: softmaxed Q weights x context -> agg bf16, 512 thr ----------
// Masked L-rows: substitute A-frag with exact bf16(1/64) (reference: uniform).
__global__ __launch_bounds__(512) void attd_k(const short* __restrict__ qb,
    const float* __restrict__ ctxP, const float* __restrict__ dloc,
    const int* __restrict__ mask, short* __restrict__ agg){
  const int lcb = blockIdx.x, h = blockIdx.y, b = blockIdx.z;
  __shared__ __align__(16) short lQ[2][64*64];
  __shared__ __align__(16) short lCt[64*64];   // [d][c] swizzled, bf16
  __shared__ float sInv[64];
  const int tid = threadIdx.x, lane = tid & 63, w = tid >> 6;
  const int grp = w >> 2, wg = w & 3;
  if (tid < 64){
    const int base = ((b*16 + h) << 9) + tid;   // 8 chunks x 64
    float den = 0.f;
    #pragma unroll
    for (int i = 0; i < 8; ++i) den += dloc[base + i*64];
    sInv[tid] = 1.0f / fmaxf(den, 1e-30f);
  }
  __syncthreads();
  { // plain sum of 8 context partials * 1/denom, transpose into lCt
    const int d = lane;
    const float* base = ctxP + ((size_t)(b*16 + h)*8 << 12);
    #pragma unroll
    for (int i=0;i<8;++i){
      const int c = w*8 + i;
      float s = 0.f;
      #pragma unroll
      for (int ch = 0; ch < 8; ++ch)
        s += base[ch*4096 + c*64 + d];
      s *= sInv[c];
      lCt[d*64 + ((((c>>3) ^ (d&7))<<3) | (c&7))] = (short)f2bf(s);
    }
  }
  const int l0g = b*LSEQ + lcb*1024 + grp*512;
  const int sl = lane & 7, rl = lane >> 3;
  const int lsw = ((sl ^ rl) << 3);
  const short uni = (short)0x3C80;               // bf16(1/64) exactly
  for (int sc = 0; sc < 8; ++sc){
    __syncthreads();                              // lQ reuse safe (prev MFMA done)
    #pragma unroll
    for (int c = 0; c < 2; ++c){
      const int r = (wg*2+c)*8 + rl;
      g2l16(qb + (size_t)(l0g + sc*64 + r)*H + h*64 + lsw, &lQ[grp][(wg*2+c)*512]);
    }
    __syncthreads();                              // loads resident (implicit vmcnt drain)
    f32x4 acc[4] = {};
    const int q4 = lane >> 4, r16 = lane & 15;
    const int rowA = wg*16 + r16;
    const int mk = mask[(size_t)l0g + sc*64 + rowA];
    #pragma unroll
    for (int kk=0;kk<2;++kk){
      const int slog = kk*4 + q4;
      bf16x8 a = *(bf16x8*)&lQ[grp][rowA*64 + ((slog ^ (rowA&7))<<3)];
      if (!mk){
        #pragma unroll
        for (int e = 0; e < 8; ++e) a[e] = uni;
      }
      #pragma unroll
      for (int ni=0;ni<4;++ni){
        const int rowB = ni*16 + r16;
        bf16x8 bv = *(bf16x8*)&lCt[rowB*64 + ((slog ^ (rowB&7))<<3)];
        acc[ni] = mfma16(a, bv, acc[ni]);
      }
    }
    #pragma unroll
    for (int ni=0;ni<4;++ni){
      const int d = ni*16 + r16;
      #pragma unroll
      for (int j=0;j<4;++j){
        const int lrow = wg*16 + q4*4 + j;
        agg[(size_t)(l0g + sc*64 + lrow)*H + h*64 + d] = (short)f2bf(acc[ni][j]);
      }
    }
  }
}

extern "C" void kernel_launch(void* const* d_in, const int* in_sizes, int n_in,
                              void* d_out, int out_size, void* d_ws, size_t ws_size,
                              hipStream_t stream){
  (void)in_sizes; (void)n_in; (void)out_size; (void)ws_size;
  const float* x    = (const float*)d_in[0];
  const int*   mask = (const int*)d_in[1];
  P4 prm;
  for (int p2 = 0; p2 < 4; ++p2){        // 0=k,1=q,2=v,3=r
    prm.dw[p2] = (const float*)d_in[2 + 4*p2];
    prm.db[p2] = (const float*)d_in[3 + 4*p2];
    prm.pw[p2] = (const float*)d_in[4 + 4*p2];
    prm.pb[p2] = (const float*)d_in[5 + 4*p2];
  }
  char* ws = (char*)d_ws;
  short* WB   = (short*)(ws);                          // 8 MiB: 4 x [H][H] bf16
  float* BIAS = (float*)(ws + ((size_t)8<<20));        // 16 KiB
  float* DLOC = (float*)(ws + ((size_t)8<<20) + (512<<10));  // 128 KiB
  short* XB   = (short*)(ws + ((size_t)9<<20));        // 32 MiB bf16 x
  short* QB   = (short*)(ws + ((size_t)41<<20));       // 32 MiB softmaxed q-weights [M][H]
  short* KT   = (short*)(ws + ((size_t)73<<20));       // 32 MiB keys^T [B][H][L]
  short* VT   = (short*)(ws + ((size_t)105<<20));      // 32 MiB values^T
  float* CTXP = (float*)(ws + ((size_t)137<<20));      // 8 MiB context partials (8 chunks)
  short* AGG  = XB;                                    // reuse (x dead after proj GEMM)

  prepcvt<<<8192, 256, 0, stream>>>(prm, x, WB, BIAS, XB);
  gemm8<0,12><<<768, 512, 0, stream>>>(XB, WB, BIAS, QB, KT, VT, nullptr);
  ctx_k<<<dim3(8,16,4), 256, 0, stream>>>(KT, VT, mask, CTXP, DLOC);
  attd_k<<<dim3(4,16,4), 512, 0, stream>>>(QB, CTXP, DLOC, mask, AGG);
  gemm8<1,4><<<256, 512, 0, stream>>>(AGG, WB + (size_t)3*H*H, BIAS + 3*1024,
                                      nullptr, nullptr, nullptr, (float*)d_out);
}

// Round 18
// 198.665 us; speedup vs baseline: 1.1222x; 1.1222x over previous
//
#include <hip/hip_runtime.h>
#include <stdint.h>

#define H 1024
#define LSEQ 4096
#define NBATCH 4
#define MT (NBATCH*LSEQ)   // 16384 rows total

typedef __attribute__((ext_vector_type(8))) short bf16x8;
typedef __attribute__((ext_vector_type(4))) short s16x4;
typedef __attribute__((ext_vector_type(4))) float f32x4;

static __device__ __forceinline__ unsigned short f2bf(float f){
  union { float f; unsigned u; } v; v.f = f;
  unsigned u = v.u;
  return (unsigned short)((u + 0x7FFFu + ((u >> 16) & 1u)) >> 16);  // RNE
}
static __device__ __forceinline__ float bf2f(unsigned short h){
  union { unsigned u; float f; } v; v.u = ((unsigned)h) << 16;
  return v.f;
}
static __device__ __forceinline__ void g2l16(const void* g, void* l){
  __builtin_amdgcn_global_load_lds((const __attribute__((address_space(1))) void*)g,
                                   (__attribute__((address_space(3))) void*)l, 16, 0, 0);
}
static __device__ __forceinline__ f32x4 mfma16(bf16x8 a, bf16x8 b, f32x4 c){
  return __builtin_amdgcn_mfma_f32_16x16x32_bf16(a, b, c, 0, 0, 0);
}

// ---------------- fused: weight prep (blocks 0..4095) + x->bf16 (4096..8191) ---
struct P4 { const float* pw[4]; const float* dw[4]; const float* db[4]; const float* pb[4]; };

__global__ __launch_bounds__(256) void prepcvt(P4 a, const float* __restrict__ x,
    short* __restrict__ wb, float* __restrict__ bo, short* __restrict__ xb){
  const int bid = blockIdx.x, t = threadIdx.x;
  if (bid < 4096){
    __shared__ float red[256];
    const int p = bid >> 10, j = bid & 1023;
    const float* row = a.pw[p] + (size_t)j * H;
    const float* dwp = a.dw[p];
    const float* dbp = a.db[p];
    float acc = 0.f;
    #pragma unroll
    for (int k = 0; k < 4; ++k){
      int i = k*256 + t;
      float pv = row[i];
      wb[((size_t)p*H + j)*H + i] = (short)f2bf(pv * dwp[i]);
      acc += dbp[i] * pv;
    }
    red[t] = acc; __syncthreads();
    for (int s = 128; s > 0; s >>= 1){
      if (t < s) red[t] += red[t+s];
      __syncthreads();
    }
    if (t == 0) bo[p*H + j] = a.pb[p][j] + red[0];
  } else {
    const size_t base = ((size_t)(bid - 4096) * 4096) + (size_t)t * 16;
    #pragma unroll
    for (int h2 = 0; h2 < 2; ++h2){
      const float4* p = (const float4*)(x + base + h2*8);
      float4 u = p[0], v = p[1];
      bf16x8 o;
      o[0]=(short)f2bf(u.x); o[1]=(short)f2bf(u.y); o[2]=(short)f2bf(u.z); o[3]=(short)f2bf(u.w);
      o[4]=(short)f2bf(v.x); o[5]=(short)f2bf(v.y); o[6]=(short)f2bf(v.z); o[7]=(short)f2bf(v.w);
      *(bf16x8*)(xb + base + h2*8) = o;
    }
  }
}

// ============== 256x256 tile, BK=64, 8-wave, 2-phase counted-vmcnt GEMM ========
// R6/R10-proven structure (1010 TF). FROZEN: K-loop (R5/R7/R8/R11/R13 regressed)
// and n-fastest intra-XCD traversal (R17's m-fastest flip regressed 108->135).
// MODE 0: N=3072 fused k|q|v. p=1 -> QB holds UNMASKED fp32-softmaxed query
//         weights (shift-free); mask handled in attd_k. p=0/2 -> KT/VT [B][H][L].
// MODE 1: N=1024, fp32 out [M][H].
template<int MODE, int NBLK>
__global__ __launch_bounds__(512, 2) void gemm8(const short* __restrict__ A,
    const short* __restrict__ WBp, const float* __restrict__ bia,
    short* __restrict__ oq, short* __restrict__ okT, short* __restrict__ ovT,
    float* __restrict__ ofin){
  __shared__ __align__(16) short lsm[2][2][256*64];

  const int nwg = NBLK * 64;
  const int cpx = nwg >> 3;
  const int bid = blockIdx.x;
  const int swz = (bid & 7) * cpx + (bid >> 3);   // XCD-contiguous chunks
  const int mb = swz / NBLK, nb = swz % NBLK;     // n fastest within XCD (proven best)
  const int m0 = mb * 256, n0 = nb * 256;

  const int tid  = threadIdx.x;
  const int lane = tid & 63;
  const int w    = tid >> 6;            // 0..7
  const int wm   = w >> 2, wn = w & 3;  // 2 x 4 wave grid; per-wave out 128x64
  const int q4 = lane >> 4, r16 = lane & 15;
  const int rl = lane >> 3, sl = lane & 7;
  const int srcsw = ((sl ^ rl) << 3);   // pre-swizzled global source slot

#define STAGE_A(BUF_, Q_, KB_) \
  g2l16(A + (size_t)(m0 + (Q_)*64 + w*8 + rl)*H + (KB_) + srcsw, \
        &lsm[0][BUF_][((Q_)*64 + w*8)*64])
#define STAGE_B(BUF_, Q_, KB_) \
  g2l16(WBp + (size_t)(n0 + (Q_)*64 + w*8 + rl)*H + (KB_) + srcsw, \
        &lsm[1][BUF_][((Q_)*64 + w*8)*64])
#define RD_A(dst, BUF_, MI8, KK) { const int row_ = wm*128 + (MI8)*16 + r16; \
  dst = *(const bf16x8*)&lsm[0][BUF_][row_*64 + ((((KK)*4+q4) ^ (row_&7))<<3)]; }
#define RD_B(dst, BUF_, NI4, KK) { const int row_ = wn*64 + (NI4)*16 + r16; \
  dst = *(const bf16x8*)&lsm[1][BUF_][row_*64 + ((((KK)*4+q4) ^ (row_&7))<<3)]; }

  f32x4 acc[8][4] = {};
  bf16x8 aF[4][2], bFa[2][2], bFb[2][2];

  // prologue: stage tile 0 (B quarters first, then A in first-needed order)
  STAGE_B(0,0,0); STAGE_B(0,1,0); STAGE_B(0,2,0); STAGE_B(0,3,0);
  STAGE_A(0,0,0); STAGE_A(0,2,0); STAGE_A(0,1,0); STAGE_A(0,3,0);
  asm volatile("s_waitcnt vmcnt(2)" ::: "memory");
  __builtin_amdgcn_s_barrier();

  #pragma unroll 2
  for (int t = 0; t < 16; ++t){
    const int buf = t & 1, sbuf = buf ^ 1;
    const int skb = ((t < 15) ? (t + 1) : 15) << 6;

    // ---- phase AB: full N, first M-half (A quarters q0/q2) ----
    #pragma unroll
    for (int mi = 0; mi < 4; ++mi){ RD_A(aF[mi][0], buf, mi, 0); RD_A(aF[mi][1], buf, mi, 1); }
    #pragma unroll
    for (int ni = 0; ni < 2; ++ni){ RD_B(bFa[ni][0], buf, ni, 0); RD_B(bFa[ni][1], buf, ni, 1); }
    #pragma unroll
    for (int ni = 0; ni < 2; ++ni){ RD_B(bFb[ni][0], buf, 2+ni, 0); RD_B(bFb[ni][1], buf, 2+ni, 1); }
    STAGE_B(sbuf, 0, skb); STAGE_B(sbuf, 1, skb);
    STAGE_B(sbuf, 2, skb); STAGE_B(sbuf, 3, skb);
    __builtin_amdgcn_s_setprio(1);
    #pragma unroll
    for (int kk = 0; kk < 2; ++kk)
      #pragma unroll
      for (int mi = 0; mi < 4; ++mi){
        #pragma unroll
        for (int ni = 0; ni < 2; ++ni)
          acc[mi][ni] = mfma16(aF[mi][kk], bFa[ni][kk], acc[mi][ni]);
        #pragma unroll
        for (int ni = 0; ni < 2; ++ni)
          acc[mi][2+ni] = mfma16(aF[mi][kk], bFb[ni][kk], acc[mi][2+ni]);
      }
    __builtin_amdgcn_s_setprio(0);
    asm volatile("s_waitcnt vmcnt(4)" ::: "memory");   // A q1/q3 of tile t landed
    __builtin_amdgcn_s_barrier();

    // ---- phase CD: full N, second M-half (A quarters q1/q3) ----
    #pragma unroll
    for (int mi = 0; mi < 4; ++mi){ RD_A(aF[mi][0], buf, 4+mi, 0); RD_A(aF[mi][1], buf, 4+mi, 1); }
    STAGE_A(sbuf, 0, skb); STAGE_A(sbuf, 2, skb);
    STAGE_A(sbuf, 1, skb); STAGE_A(sbuf, 3, skb);
    __builtin_amdgcn_s_setprio(1);
    #pragma unroll
    for (int kk = 0; kk < 2; ++kk)
      #pragma unroll
      for (int mi = 0; mi < 4; ++mi){
        #pragma unroll
        for (int ni = 0; ni < 2; ++ni)
          acc[4+mi][ni] = mfma16(aF[mi][kk], bFa[ni][kk], acc[4+mi][ni]);
        #pragma unroll
        for (int ni = 0; ni < 2; ++ni)
          acc[4+mi][2+ni] = mfma16(aF[mi][kk], bFb[ni][kk], acc[4+mi][2+ni]);
      }
    __builtin_amdgcn_s_setprio(0);
    asm volatile("s_waitcnt vmcnt(2)" ::: "memory");   // next tile's B + A q0/q2 landed
    __builtin_amdgcn_s_barrier();
  }
#undef STAGE_A
#undef STAGE_B
#undef RD_A
#undef RD_B

  // ---------------- epilogue ----------------
  if (MODE == 1){
    #pragma unroll
    for (int ni4 = 0; ni4 < 4; ++ni4){
      const int n = n0 + wn*64 + ni4*16 + r16;
      const float bv = bia[n];
      #pragma unroll
      for (int mi8 = 0; mi8 < 8; ++mi8){
        const int mbse = m0 + wm*128 + mi8*16 + q4*4;
        #pragma unroll
        for (int j = 0; j < 4; ++j)
          ofin[(size_t)(mbse+j)*H + n] = acc[mi8][ni4][j] + bv;
      }
    }
  } else {
    const int p = n0 >> 10;
    if (p == 1){
      // queries: shift-free fp32 softmax over the head's 64 channels (4 regs x
      // 16 lanes, constant q4,j), UNMASKED -> attd_k substitutes masked rows.
      #pragma unroll
      for (int ni4 = 0; ni4 < 4; ++ni4){
        const float bv = bia[n0 + wn*64 + ni4*16 + r16];
        #pragma unroll
        for (int mi8 = 0; mi8 < 8; ++mi8)
          #pragma unroll
          for (int j = 0; j < 4; ++j)
            acc[mi8][ni4][j] += bv;
      }
      #pragma unroll
      for (int mi8 = 0; mi8 < 8; ++mi8){
        #pragma unroll
        for (int j = 0; j < 4; ++j){
          float e0 = __expf(acc[mi8][0][j]);
          float e1 = __expf(acc[mi8][1][j]);
          float e2 = __expf(acc[mi8][2][j]);
          float e3 = __expf(acc[mi8][3][j]);
          float s = e0 + e1 + e2 + e3;
          s += __shfl_xor(s, 1);
          s += __shfl_xor(s, 2);
          s += __shfl_xor(s, 4);
          s += __shfl_xor(s, 8);
          const float inv = 1.0f / s;
          acc[mi8][0][j] = e0*inv;
          acc[mi8][1][j] = e1*inv;
          acc[mi8][2][j] = e2*inv;
          acc[mi8][3][j] = e3*inv;
        }
      }
      #pragma unroll
      for (int ni4 = 0; ni4 < 4; ++ni4){
        const int ch = (n0 & 1023) + wn*64 + ni4*16 + r16;
        #pragma unroll
        for (int mi8 = 0; mi8 < 8; ++mi8){
          const int mbse = m0 + wm*128 + mi8*16 + q4*4;
          #pragma unroll
          for (int j = 0; j < 4; ++j)
            oq[(size_t)(mbse+j)*H + ch] = (short)f2bf(acc[mi8][ni4][j]);
        }
      }
    } else {                                      // k/v -> transposed [B][H][L] via LDS stage
      asm volatile("s_waitcnt vmcnt(0)" ::: "memory");
      __syncthreads();
      char* sC = (char*)&lsm[0][0][0];            // 128 KiB = 256 ch x 256 m bf16, 512B rows
      #pragma unroll
      for (int ni4 = 0; ni4 < 4; ++ni4){
        const int cr = wn*64 + ni4*16 + r16;      // tile row = channel
        const float bv = bia[n0 + cr];
        #pragma unroll
        for (int mi8 = 0; mi8 < 8; ++mi8){
          const int s8 = wm*32 + mi8*4 + q4;      // 8B slot along m
          s16x4 v;
          #pragma unroll
          for (int j = 0; j < 4; ++j) v[j] = (short)f2bf(acc[mi8][ni4][j] + bv);
          *(s16x4*)(sC + cr*512 + ((s8 ^ ((cr & 7) << 1)) << 3)) = v;
        }
      }
      __syncthreads();
      short* ot = (p == 0) ? okT : ovT;
      const int ch0 = n0 & 1023, bb = m0 >> 12, lp0 = m0 & 4095;
      const int c = lane & 31;
      #pragma unroll
      for (int it = 0; it < 16; ++it){
        const int cr = it*16 + w*2 + (lane >> 5);
        bf16x8 vv = *(bf16x8*)(sC + cr*512 + ((c ^ (cr & 7)) << 4));
        *(bf16x8*)&ot[((size_t)bb*H + ch0 + cr)*LSEQ + lp0 + c*8] = vv;
      }
    }
  }
}

// ------- context partial over a 512-L chunk, fixed-shift softmax ---------------
// 256-thread blocks, serial 8-kc loop, double-buffered stage-ahead (R14-proven).
// w = mask ? exp(k-8) : 0 (scale cancels in (Sum w*v)/(Sum w)).
__global__ __launch_bounds__(256) void ctx_k(const short* __restrict__ kT,
    const short* __restrict__ vT, const int* __restrict__ mask,
    float* __restrict__ ctxP, float* __restrict__ dloc){
  const int lc = blockIdx.x, h = blockIdx.y, b = blockIdx.z;   // lc 0..7
  __shared__ __align__(16) short lK[2][64*64];
  __shared__ __align__(16) short lV[2][64*64];
  __shared__ int sMk[2][64];
  __shared__ float sDen[4][64];
  const int tid = threadIdx.x, lane = tid & 63, w = tid >> 6;  // w 0..3
  const short* kb = kT + (size_t)(b*16 + h)*64*LSEQ;
  const short* vb = vT + (size_t)(b*16 + h)*64*LSEQ;
  const int l0 = lc*512;
  const int sl = lane & 7, rl = lane >> 3;
  const int lsw = ((sl ^ rl) << 3);

#define CSTAGE(BUF_, KC_) { const int lb_ = l0 + (KC_)*64; \
  const int r0_ = (w*2)*8 + rl, r1_ = (w*2+1)*8 + rl; \
  g2l16(kb + (size_t)r0_*LSEQ + lb_ + lsw, &lK[BUF_][(w*2)*512]); \
  g2l16(vb + (size_t)r0_*LSEQ + lb_ + lsw, &lV[BUF_][(w*2)*512]); \
  g2l16(kb + (size_t)r1_*LSEQ + lb_ + lsw, &lK[BUF_][(w*2+1)*512]); \
  g2l16(vb + (size_t)r1_*LSEQ + lb_ + lsw, &lV[BUF_][(w*2+1)*512]); \
  if (tid < 64) sMk[BUF_][tid] = mask[(size_t)b*LSEQ + lb_ + tid]; }

  f32x4 acc[4] = {};
  float dsum = 0.f;

  // prologue: stage kc=0 into buf 0
  CSTAGE(0, 0);
  asm volatile("s_waitcnt vmcnt(0) lgkmcnt(0)" ::: "memory");
  __builtin_amdgcn_s_barrier();

  for (int kc = 0; kc < 8; ++kc){
    const int buf = kc & 1, sbuf = buf ^ 1;
    if (kc < 7) CSTAGE(sbuf, kc + 1);             // stage-ahead: latency hidden under below
    { // in-place transform lK[buf]: k -> mask ? exp(k-8) : 0, bf16; local denom
      const int row = lane;
      #pragma unroll
      for (int k2 = 0; k2 < 2; ++k2){
        const int slog = w*2 + k2;
        const int sp = slog ^ (row & 7);
        bf16x8 v = *(bf16x8*)&lK[buf][row*64 + (sp<<3)];
        bf16x8 o;
        #pragma unroll
        for (int e = 0; e < 8; ++e){
          const float f = bf2f((unsigned short)v[e]);
          const float we = sMk[buf][slog*8+e] ? __expf(f - 8.0f) : 0.0f;
          dsum += we;
          o[e] = (short)f2bf(we);
        }
        *(bf16x8*)&lK[buf][row*64 + (sp<<3)] = o;
      }
    }
    asm volatile("s_waitcnt lgkmcnt(0)" ::: "memory");  // my transform writes done
    __builtin_amdgcn_s_barrier();                       // all transforms visible
    {
      const int q4 = lane >> 4, r16 = lane & 15;
      #pragma unroll
      for (int kk = 0; kk < 2; ++kk){
        const int slog = kk*4 + q4;
        const int rowA = w*16 + r16;
        bf16x8 a = *(bf16x8*)&lK[buf][rowA*64 + ((slog ^ (rowA & 7))<<3)];
        #pragma unroll
        for (int ni = 0; ni < 4; ++ni){
          const int rowB = ni*16 + r16;
          bf16x8 bv = *(bf16x8*)&lV[buf][rowB*64 + ((slog ^ (rowB & 7))<<3)];
          acc[ni] = mfma16(a, bv, acc[ni]);
        }
      }
    }
    asm volatile("s_waitcnt vmcnt(0) lgkmcnt(0)" ::: "memory");  // kc+1 resident
    __builtin_amdgcn_s_barrier();
  }
#undef CSTAGE

  const int q4 = lane >> 4, r16 = lane & 15;
  float* op = ctxP + (((size_t)(b*16 + h)*8 + lc) << 12);
  #pragma unroll
  for (int ni = 0; ni < 4; ++ni){
    const int d = ni*16 + r16;
    #pragma unroll
    for (int j = 0; j < 4; ++j){
      const int c = w*16 + q4*4 + j;
      op[c*64 + d] = acc[ni][j];
    }
  }
  sDen[w][lane] = dsum;
  __syncthreads();
  if (tid < 64){
    const int idx = (((b*16 + h)*8 + lc) << 6) + tid;
    dloc[idx] = sDen[0][tid] + sDen[1][tid] + sDen[2][tid] + sDen[3][tid];
  }
}

// ------- attended: softmaxed Q weights x context -> agg bf16, 512 thr ----------
// Masked L-rows: substitute A-frag with exact bf16(1/64) (reference: uniform).
__global__ __launch_bounds__(512) void attd_k(const short* __restrict__ qb,
    const float* __restrict__ ctxP, const float* __restrict__ dloc,
    const int* __restrict__ mask, short* __restrict__ agg){
  const int lcb = blockIdx.x, h = blockIdx.y, b = blockIdx.z;
  __shared__ __align__(16) short lQ[2][64*64];
  __shared__ __align__(16) short lCt[64*64];   // [d][c] swizzled, bf16
  __shared__ float sInv[64];
  const int tid = threadIdx.x, lane = tid & 63, w = tid >> 6;
  const int grp = w >> 2, wg = w & 3;
  if (tid < 64){
    const int base = ((b*16 + h) << 9) + tid;   // 8 chunks x 64
    float den = 0.f;
    #pragma unroll
    for (int i = 0; i < 8; ++i) den += dloc[base + i*64];
    sInv[tid] = 1.0f / fmaxf(den, 1e-30f);
  }
  __syncthreads();
  { // plain sum of 8 context partials * 1/denom, transpose into lCt
    const int d = lane;
    const float* base = ctxP + ((size_t)(b*16 + h)*8 << 12);
    #pragma unroll
    for (int i=0;i<8;++i){
      const int c = w*8 + i;
      float s = 0.f;
      #pragma unroll
      for (int ch = 0; ch < 8; ++ch)
        s += base[ch*4096 + c*64 + d];
      s *= sInv[c];
      lCt[d*64 + ((((c>>3) ^ (d&7))<<3) | (c&7))] = (short)f2bf(s);
    }
  }
  const int l0g = b*LSEQ + lcb*1024 + grp*512;
  const int sl = lane & 7, rl = lane >> 3;
  const int lsw = ((sl ^ rl) << 3);
  const short uni = (short)0x3C80;               // bf16(1/64) exactly
  for (int sc = 0; sc < 8; ++sc){
    __syncthreads();                              // lQ reuse safe (prev MFMA done)
    #pragma unroll
    for (int c = 0; c < 2; ++c){
      const int r = (wg*2+c)*8 + rl;
      g2l16(qb + (size_t)(l0g + sc*64 + r)*H + h*64 + lsw, &lQ[grp][(wg*2+c)*512]);
    }
    __syncthreads();                              // loads resident (implicit vmcnt drain)
    f32x4 acc[4] = {};
    const int q4 = lane >> 4, r16 = lane & 15;
    const int rowA = wg*16 + r16;
    const int mk = mask[(size_t)l0g + sc*64 + rowA];
    #pragma unroll
    for (int kk=0;kk<2;++kk){
      const int slog = kk*4 + q4;
      bf16x8 a = *(bf16x8*)&lQ[grp][rowA*64 + ((slog ^ (rowA&7))<<3)];
      if (!mk){
        #pragma unroll
        for (int e = 0; e < 8; ++e) a[e] = uni;
      }
      #pragma unroll
      for (int ni=0;ni<4;++ni){
        const int rowB = ni*16 + r16;
        bf16x8 bv = *(bf16x8*)&lCt[rowB*64 + ((slog ^ (rowB&7))<<3)];
        acc[ni] = mfma16(a, bv, acc[ni]);
      }
    }
    #pragma unroll
    for (int ni=0;ni<4;++ni){
      const int d = ni*16 + r16;
      #pragma unroll
      for (int j=0;j<4;++j){
        const int lrow = wg*16 + q4*4 + j;
        agg[(size_t)(l0g + sc*64 + lrow)*H + h*64 + d] = (short)f2bf(acc[ni][j]);
      }
    }
  }
}

extern "C" void kernel_launch(void* const* d_in, const int* in_sizes, int n_in,
                              void* d_out, int out_size, void* d_ws, size_t ws_size,
                              hipStream_t stream){
  (void)in_sizes; (void)n_in; (void)out_size; (void)ws_size;
  const float* x    = (const float*)d_in[0];
  const int*   mask = (const int*)d_in[1];
  P4 prm;
  for (int p2 = 0; p2 < 4; ++p2){        // 0=k,1=q,2=v,3=r
    prm.dw[p2] = (const float*)d_in[2 + 4*p2];
    prm.db[p2] = (const float*)d_in[3 + 4*p2];
    prm.pw[p2] = (const float*)d_in[4 + 4*p2];
    prm.pb[p2] = (const float*)d_in[5 + 4*p2];
  }
  char* ws = (char*)d_ws;
  short* WB   = (short*)(ws);                          // 8 MiB: 4 x [H][H] bf16
  float* BIAS = (float*)(ws + ((size_t)8<<20));        // 16 KiB
  float* DLOC = (float*)(ws + ((size_t)8<<20) + (512<<10));  // 128 KiB
  short* XB   = (short*)(ws + ((size_t)9<<20));        // 32 MiB bf16 x
  short* QB   = (short*)(ws + ((size_t)41<<20));       // 32 MiB softmaxed q-weights [M][H]
  short* KT   = (short*)(ws + ((size_t)73<<20));       // 32 MiB keys^T [B][H][L]
  short* VT   = (short*)(ws + ((size_t)105<<20));      // 32 MiB values^T
  float* CTXP = (float*)(ws + ((size_t)137<<20));      // 8 MiB context partials (8 chunks)
  short* AGG  = XB;                                    // reuse (x dead after proj GEMM)

  prepcvt<<<8192, 256, 0, stream>>>(prm, x, WB, BIAS, XB);
  gemm8<0,12><<<768, 512, 0, stream>>>(XB, WB, BIAS, QB, KT, VT, nullptr);
  ctx_k<<<dim3(8,16,4), 256, 0, stream>>>(KT, VT, mask, CTXP, DLOC);
  attd_k<<<dim3(4,16,4), 512, 0, stream>>>(QB, CTXP, DLOC, mask, AGG);
  gemm8<1,4><<<256, 512, 0, stream>>>(AGG, WB + (size_t)3*H*H, BIAS + 3*1024,
                                      nullptr, nullptr, nullptr, (float*)d_out);
}